// Round 1
// baseline (1148.405 us; speedup 1.0000x reference)
//
#include <hip/hip_runtime.h>
#include <math.h>

#define BB 2
#define SS 2048
#define EE 1024
#define HH 16
#define DD 64

// ---------------------------------------------------------------------------
// GEMM: out[m,n] = sum_k X[m,k]*W[n,k] + bias[n]
// X: [M=4096, K=1024] row-major, W: [N=1024, K=1024] row-major (torch Linear)
// Tile 64x64, KT=16, 256 threads, 4x4 accum per thread. fp32 VALU.
// SCATTER=1: write to [B,H,S,D] layout (for Q/K/V). SCATTER=0: row-major.
// ---------------------------------------------------------------------------
template<int SCATTER>
__global__ __launch_bounds__(256)
void gemm64(const float* __restrict__ X, const float* __restrict__ W,
            const float* __restrict__ bias, float* __restrict__ out)
{
    const int K = 1024;
    __shared__ __align__(16) float As[16][68];   // As[k][m], +4 pad keeps rows 16B-aligned
    __shared__ __align__(16) float Bs[16][68];   // Bs[k][n]
    const int t  = threadIdx.x;
    const int m0 = blockIdx.y * 64;
    const int n0 = blockIdx.x * 64;
    const int tr = t >> 4;          // 0..15 (output row group)
    const int tc = t & 15;          // 0..15 (output col group)
    const int lrow = t >> 2;        // 0..63 (staging row)
    const int lk   = (t & 3) * 4;   // 0,4,8,12 (staging k offset)
    const float* Xp = X + (size_t)(m0 + lrow) * K + lk;
    const float* Wp = W + (size_t)(n0 + lrow) * K + lk;
    float acc[4][4] = {{0.f,0.f,0.f,0.f},{0.f,0.f,0.f,0.f},
                       {0.f,0.f,0.f,0.f},{0.f,0.f,0.f,0.f}};
    for (int k0 = 0; k0 < K; k0 += 16) {
        float4 xa = *(const float4*)(Xp + k0);
        float4 wa = *(const float4*)(Wp + k0);
        __syncthreads();   // protect previous iteration's LDS reads
        As[lk+0][lrow] = xa.x; As[lk+1][lrow] = xa.y;
        As[lk+2][lrow] = xa.z; As[lk+3][lrow] = xa.w;
        Bs[lk+0][lrow] = wa.x; Bs[lk+1][lrow] = wa.y;
        Bs[lk+2][lrow] = wa.z; Bs[lk+3][lrow] = wa.w;
        __syncthreads();
        #pragma unroll
        for (int kk = 0; kk < 16; kk++) {
            float4 a = *(const float4*)&As[kk][tr*4];
            float4 b = *(const float4*)&Bs[kk][tc*4];
            float av[4] = {a.x, a.y, a.z, a.w};
            float bv[4] = {b.x, b.y, b.z, b.w};
            #pragma unroll
            for (int i = 0; i < 4; i++)
                #pragma unroll
                for (int j = 0; j < 4; j++)
                    acc[i][j] = fmaf(av[i], bv[j], acc[i][j]);
        }
    }
    float bj[4];
    #pragma unroll
    for (int j = 0; j < 4; j++) bj[j] = bias[n0 + tc*4 + j];
    #pragma unroll
    for (int i = 0; i < 4; i++) {
        const int m = m0 + tr*4 + i;
        float4 st;
        st.x = acc[i][0] + bj[0];
        st.y = acc[i][1] + bj[1];
        st.z = acc[i][2] + bj[2];
        st.w = acc[i][3] + bj[3];
        if (SCATTER) {
            // n-tile (64 wide, 64-aligned) covers exactly one head
            const int b = m >> 11;          // m / 2048
            const int s = m & 2047;
            const int h = n0 >> 6;
            *(float4*)&out[(((size_t)(b*HH + h))*SS + s)*DD + tc*4] = st;
        } else {
            *(float4*)&out[(size_t)m*EE + n0 + tc*4] = st;
        }
    }
}

// ---------------------------------------------------------------------------
// Causal flash attention, fp32. Q/K/V in [B,H,S,D] (D=64).
// Block = 256 threads = 4 waves, handles 128 Q rows: 64 from row-group gA
// and 64 from mirror group gB = 31-gA (constant total work per block).
// Each wave owns 32 rows; lanes l and l^32 split the 64 d's of one row
// (dot combined via shfl_xor(32)). Online softmax w/ deferred-max (THR=8).
// K/V tiles (64x64 fp32 each, 32 KB) staged cooperatively in LDS.
// Writes concat layout [B,S,E].
// ---------------------------------------------------------------------------
__global__ __launch_bounds__(256)
void attn_fwd(const float* __restrict__ Q, const float* __restrict__ Kg,
              const float* __restrict__ V, float* __restrict__ Oc)
{
    __shared__ __align__(16) float Ks[64][64];
    __shared__ __align__(16) float Vs[64][64];
    const int bh = blockIdx.x;           // 0..31  (b*H + h)
    const int b  = bh >> 4;
    const int h  = bh & 15;
    const int cpair = blockIdx.y;        // 0..15
    const int gA = cpair;
    const int gB = 31 - cpair;
    const int t = threadIdx.x;
    const int w = t >> 6;                // wave 0..3
    const int lane  = t & 63;
    const int rowin = lane & 31;
    const int dhalf = lane >> 5;
    const int grp = (w < 2) ? gA : gB;
    const int q   = grp*64 + (w & 1)*32 + rowin;   // this lane's query row
    const int d0  = dhalf * 32;

    const float* Qb = Q  + (size_t)bh * SS * DD;
    const float* Kb = Kg + (size_t)bh * SS * DD;
    const float* Vb = V  + (size_t)bh * SS * DD;

    float qr[32];
    #pragma unroll
    for (int i = 0; i < 8; i++) {
        float4 v4 = *(const float4*)&Qb[(size_t)q*DD + d0 + i*4];
        qr[i*4+0]=v4.x; qr[i*4+1]=v4.y; qr[i*4+2]=v4.z; qr[i*4+3]=v4.w;
    }
    float o[32];
    #pragma unroll
    for (int i = 0; i < 32; i++) o[i] = 0.f;
    float mrun = -INFINITY, lrun = 0.f;

    const int srow = t >> 4;        // staging: 0..15
    const int sc4  = (t & 15) * 4;

    const int ktiles = gB + 1;      // keys up to 64*gB+63 = max q in block
    for (int kt = 0; kt < ktiles; kt++) {
        const int k0 = kt * 64;
        __syncthreads();
        #pragma unroll
        for (int p = 0; p < 4; p++) {
            const int r = p*16 + srow;
            *(float4*)&Ks[r][sc4] = *(const float4*)&Kb[(size_t)(k0 + r)*DD + sc4];
            *(float4*)&Vs[r][sc4] = *(const float4*)&Vb[(size_t)(k0 + r)*DD + sc4];
        }
        __syncthreads();
        int kmax = q - k0 + 1;      // causal: keys k0..k0+kmax-1 allowed
        if (kmax > 64) kmax = 64;
        for (int kk = 0; kk < kmax; kk++) {
            float p0=0.f, p1=0.f, p2=0.f, p3=0.f;
            #pragma unroll
            for (int i = 0; i < 8; i++) {
                float4 kv = *(const float4*)&Ks[kk][d0 + i*4];
                p0 = fmaf(qr[i*4+0], kv.x, p0);
                p1 = fmaf(qr[i*4+1], kv.y, p1);
                p2 = fmaf(qr[i*4+2], kv.z, p2);
                p3 = fmaf(qr[i*4+3], kv.w, p3);
            }
            float part = (p0+p1) + (p2+p3);
            float sc = (part + __shfl_xor(part, 32)) * 0.125f;  // /sqrt(64)
            if (sc > mrun + 8.f) {              // deferred-max rescale (T13)
                float alpha = __expf(mrun - sc);
                mrun = sc;
                lrun *= alpha;
                #pragma unroll
                for (int i = 0; i < 32; i++) o[i] *= alpha;
            }
            float pexp = __expf(sc - mrun);
            lrun += pexp;
            #pragma unroll
            for (int i = 0; i < 8; i++) {
                float4 vv = *(const float4*)&Vs[kk][d0 + i*4];
                o[i*4+0] = fmaf(pexp, vv.x, o[i*4+0]);
                o[i*4+1] = fmaf(pexp, vv.y, o[i*4+1]);
                o[i*4+2] = fmaf(pexp, vv.z, o[i*4+2]);
                o[i*4+3] = fmaf(pexp, vv.w, o[i*4+3]);
            }
        }
    }
    const float inv = 1.f / lrun;
    float* op = Oc + ((size_t)b*SS + q)*EE + h*DD + d0;
    #pragma unroll
    for (int i = 0; i < 8; i++) {
        float4 st;
        st.x = o[i*4+0]*inv; st.y = o[i*4+1]*inv;
        st.z = o[i*4+2]*inv; st.w = o[i*4+3]*inv;
        *(float4*)&op[i*4] = st;
    }
}

extern "C" void kernel_launch(void* const* d_in, const int* in_sizes, int n_in,
                              void* d_out, int out_size, void* d_ws, size_t ws_size,
                              hipStream_t stream)
{
    (void)in_sizes; (void)n_in; (void)out_size; (void)ws_size;
    const float* query = (const float*)d_in[0];
    const float* key   = (const float*)d_in[1];
    const float* value = (const float*)d_in[2];
    // d_in[3] = mask (int32): exactly causal tril -> implemented analytically
    const float* Wq = (const float*)d_in[4];
    const float* bq = (const float*)d_in[5];
    const float* Wk = (const float*)d_in[6];
    const float* bk = (const float*)d_in[7];
    const float* Wv = (const float*)d_in[8];
    const float* bv = (const float*)d_in[9];
    const float* Wo = (const float*)d_in[10];
    const float* bo = (const float*)d_in[11];
    float* out = (float*)d_out;

    const size_t NE = (size_t)BB * SS * EE;   // 4,194,304 elements (16 MB)
    float* Qw = (float*)d_ws;                 // [B,H,S,D]
    float* Kw = Qw + NE;
    float* Vw = Kw + NE;
    float* Cw = Vw + NE;                      // concat [B,S,E]

    dim3 blk(256);
    dim3 g1(EE/64, (BB*SS)/64);               // (16, 64)
    gemm64<1><<<g1, blk, 0, stream>>>(query, Wq, bq, Qw);
    gemm64<1><<<g1, blk, 0, stream>>>(key,   Wk, bk, Kw);
    gemm64<1><<<g1, blk, 0, stream>>>(value, Wv, bv, Vw);
    attn_fwd<<<dim3(BB*HH, 16), blk, 0, stream>>>(Qw, Kw, Vw, Cw);
    gemm64<0><<<g1, blk, 0, stream>>>(Cw, Wo, bo, out);
}

// Round 2
// 199.133 us; speedup vs baseline: 5.7670x; 5.7670x over previous
//
#include <hip/hip_runtime.h>
#include <math.h>

#define BB 2
#define SS 2048
#define EE 1024
#define HH 16
#define DD 64

typedef unsigned short u16;
typedef __attribute__((ext_vector_type(8))) short short8;
typedef __attribute__((ext_vector_type(4))) float f32x4;

__device__ __forceinline__ u16 f2bf(float x) {
    union { float f; unsigned u; } v; v.f = x;
    return (u16)((v.u + 0x7fffu + ((v.u >> 16) & 1u)) >> 16);
}

#define GLL16(gp, lp) \
    __builtin_amdgcn_global_load_lds( \
        (const __attribute__((address_space(1))) void*)(gp), \
        (__attribute__((address_space(3))) void*)(lp), 16, 0, 0)

// ---------------------------------------------------------------------------
// fp32 -> bf16 conversion: z = 0..2 activations (4M elems), 3..6 weights (1M)
// ---------------------------------------------------------------------------
__global__ __launch_bounds__(256)
void cvt_bf16(const float* __restrict__ s0, const float* __restrict__ s1,
              const float* __restrict__ s2, const float* __restrict__ s3,
              const float* __restrict__ s4, const float* __restrict__ s5,
              const float* __restrict__ s6,
              u16* __restrict__ d0, u16* __restrict__ d1, u16* __restrict__ d2,
              u16* __restrict__ d3, u16* __restrict__ d4, u16* __restrict__ d5,
              u16* __restrict__ d6)
{
    const int z = blockIdx.y;
    const float* s; u16* d; int n;
    switch (z) {
        case 0: s = s0; d = d0; n = 4194304; break;
        case 1: s = s1; d = d1; n = 4194304; break;
        case 2: s = s2; d = d2; n = 4194304; break;
        case 3: s = s3; d = d3; n = 1048576; break;
        case 4: s = s4; d = d4; n = 1048576; break;
        case 5: s = s5; d = d5; n = 1048576; break;
        default: s = s6; d = d6; n = 1048576; break;
    }
    const int i = (blockIdx.x * 256 + threadIdx.x) * 8;
    if (i >= n) return;
    float4 a = *(const float4*)(s + i);
    float4 b = *(const float4*)(s + i + 4);
    short8 r;
    r[0] = (short)f2bf(a.x); r[1] = (short)f2bf(a.y);
    r[2] = (short)f2bf(a.z); r[3] = (short)f2bf(a.w);
    r[4] = (short)f2bf(b.x); r[5] = (short)f2bf(b.y);
    r[6] = (short)f2bf(b.z); r[7] = (short)f2bf(b.w);
    *(short8*)(d + i) = r;
}

// ---------------------------------------------------------------------------
// bf16 MFMA GEMM: C[m,n] = sum_k X[m,k]*W[n,k] + bias[n]
// X: [4096,1024] bf16 row-major, W: [1024,1024] bf16 row-major.
// Tile 128x128, BK=32, 256 thr = 4 waves (2x2 of 64x64), 16x16x32 MFMA.
// MODE 0: Q scatter  [b,h][s][d] bf16, scaled by 0.125
// MODE 1: K scatter  [b,h][s][d] bf16
// MODE 2: V scatter  [b,h][d][s] bf16 (transposed)
// MODE 3: fp32 row-major out + bias
// LDS layout As[kgrp][m][8] so fragment reads are 16B-contiguous per lane and
// global_load_lds dests are linear in lane order.
// ---------------------------------------------------------------------------
template<int MODE>
__global__ __launch_bounds__(256)
void gemm_mfma(const u16* __restrict__ Xb, const u16* __restrict__ Wb,
               const float* __restrict__ bias, void* __restrict__ outp)
{
    __shared__ __align__(16) u16 As[4][128][8];   // 8 KB
    __shared__ __align__(16) u16 Bs[4][128][8];   // 8 KB
    const int t = threadIdx.x;
    const int w = t >> 6, l = t & 63;
    const int ln = l & 15, hi = l >> 4;
    const int m0 = blockIdx.y * 128, n0 = blockIdx.x * 128;
    const int wr = w >> 1, wc = w & 1;

    f32x4 acc[4][4];
    #pragma unroll
    for (int i = 0; i < 4; i++)
        #pragma unroll
        for (int j = 0; j < 4; j++)
            acc[i][j] = (f32x4){0.f, 0.f, 0.f, 0.f};

    for (int k0 = 0; k0 < 1024; k0 += 32) {
        __syncthreads();
        #pragma unroll
        for (int i = 0; i < 4; i++) {
            const int id = w + i * 4;              // 0..15, disjoint
            const int tensor = id >> 3, kgrp = (id >> 1) & 3, mh = id & 1;
            const u16* g = tensor ? Wb : Xb;
            const int row = (tensor ? n0 : m0) + mh * 64 + l;
            const u16* gp = g + (size_t)row * 1024 + k0 + kgrp * 8;
            u16* lp = tensor ? &Bs[kgrp][mh * 64][0] : &As[kgrp][mh * 64][0];
            GLL16(gp, lp);
        }
        __syncthreads();
        short8 af[4], bfr[4];
        #pragma unroll
        for (int mi = 0; mi < 4; mi++)
            af[mi] = *(const short8*)&As[hi][wr * 64 + mi * 16 + ln][0];
        #pragma unroll
        for (int nj = 0; nj < 4; nj++)
            bfr[nj] = *(const short8*)&Bs[hi][wc * 64 + nj * 16 + ln][0];
        #pragma unroll
        for (int mi = 0; mi < 4; mi++)
            #pragma unroll
            for (int nj = 0; nj < 4; nj++)
                acc[mi][nj] = __builtin_amdgcn_mfma_f32_16x16x32_bf16(
                    af[mi], bfr[nj], acc[mi][nj], 0, 0, 0);
    }

    // Epilogue. C layout: lane holds C[row=hi*4+r][col=ln] per 16x16 frag.
    #pragma unroll
    for (int mi = 0; mi < 4; mi++) {
        #pragma unroll
        for (int nj = 0; nj < 4; nj++) {
            const int nb = n0 + wc * 64 + nj * 16 + ln;
            const float bv = bias[nb];
            #pragma unroll
            for (int r = 0; r < 4; r++) {
                const int m = m0 + wr * 64 + mi * 16 + hi * 4 + r;
                float v = acc[mi][nj][r] + bv;
                if (MODE == 0) v *= 0.125f;
                if (MODE == 3) {
                    ((float*)outp)[(size_t)m * 1024 + nb] = v;
                } else {
                    const int b = m >> 11, s = m & 2047;
                    const int h = nb >> 6, d = nb & 63;
                    u16* o = (u16*)outp;
                    if (MODE == 2)
                        o[(((size_t)(b * HH + h) * 64 + d) << 11) + s] = f2bf(v);
                    else
                        o[((((size_t)(b * HH + h)) << 11) + s) * 64 + d] = f2bf(v);
                }
            }
        }
    }
}

// ---------------------------------------------------------------------------
// Flash attention, bf16 MFMA. Q,K: [b,h][s][d] bf16 (Q pre-scaled by 1/8),
// Vt: [b,h][d][s] bf16. Output concat [b][s][e] bf16.
// Block: 256 thr = 4 waves; wave w owns q columns q0+w*16+ln. KBLK=64.
// Swapped QK^T: ST = mfma(K_frag, Q_frag) -> lane holds scores for q=ln,
// keys = key0 + kt4*16 + hi*4 + r. Softmax row-reduce = 2 shfl_xor.
// P -> LDS (bf16, padded stride 72) -> A-frags for PV.
// ---------------------------------------------------------------------------
__global__ __launch_bounds__(256)
void attn_mfma(const u16* __restrict__ Qh, const u16* __restrict__ Kh,
               const u16* __restrict__ Vt, u16* __restrict__ Cc)
{
    __shared__ __align__(16) u16 Ks[2][4][64][8];   // [dchunk][kgrp][key][8] 8KB
    __shared__ __align__(16) u16 Vs[2][4][64][8];   // [keychunk][kgrp][d][8] 8KB
    __shared__ __align__(16) u16 Ps[4][16][72];     // per-wave [q][key], 9.2KB
    const int bh = blockIdx.x;
    const int y  = 31 - blockIdx.y;        // longest blocks dispatch first
    const int q0 = y * 64;
    const int t = threadIdx.x, w = t >> 6, l = t & 63;
    const int ln = l & 15, hi = l >> 4;
    const size_t base = (size_t)bh * SS * DD;
    const int qg = q0 + w * 16 + ln;       // this lane's q row

    short8 qf0, qf1;
    {
        const u16* qp = Qh + base + (size_t)qg * 64 + hi * 8;
        qf0 = *(const short8*)qp;          // d in [hi*8, hi*8+8)   (chunk 0)
        qf1 = *(const short8*)(qp + 32);   // d in [32+hi*8, ...)   (chunk 1)
    }
    f32x4 o[4];
    #pragma unroll
    for (int dj = 0; dj < 4; dj++) o[dj] = (f32x4){0.f, 0.f, 0.f, 0.f};
    float mrun = -INFINITY, lrun = 0.f;

    const int nkt = y + 1;
    for (int kt = 0; kt < nkt; kt++) {
        const int key0 = kt * 64;
        __syncthreads();
        #pragma unroll
        for (int i = 0; i < 4; i++) {
            const int id = w + i * 4;      // 0..7 = K tile, 8..15 = V tile
            if (id < 8) {
                const int dc = id >> 2, kg = id & 3;
                const u16* gp = Kh + base + (size_t)(key0 + l) * 64 + dc * 32 + kg * 8;
                GLL16(gp, &Ks[dc][kg][0][0]);
            } else {
                const int kc = (id >> 2) & 1, kg = id & 3;
                const u16* gp = Vt + base + (size_t)l * SS + key0 + kc * 32 + kg * 8;
                GLL16(gp, &Vs[kc][kg][0][0]);
            }
        }
        __syncthreads();

        // QK^T (swapped): st[kt4] has rows=keys, cols=q
        f32x4 st[4];
        #pragma unroll
        for (int kt4 = 0; kt4 < 4; kt4++) {
            short8 ka = *(const short8*)&Ks[0][hi][kt4 * 16 + ln][0];
            short8 kb = *(const short8*)&Ks[1][hi][kt4 * 16 + ln][0];
            f32x4 z = (f32x4){0.f, 0.f, 0.f, 0.f};
            z = __builtin_amdgcn_mfma_f32_16x16x32_bf16(ka, qf0, z, 0, 0, 0);
            z = __builtin_amdgcn_mfma_f32_16x16x32_bf16(kb, qf1, z, 0, 0, 0);
            st[kt4] = z;
        }
        if (kt == y) {  // diagonal tile: causal mask
            #pragma unroll
            for (int kt4 = 0; kt4 < 4; kt4++)
                #pragma unroll
                for (int r = 0; r < 4; r++)
                    if (key0 + kt4 * 16 + hi * 4 + r > qg)
                        st[kt4][r] = -INFINITY;
        }

        // online softmax, state per lane for q = ln
        float tmax = -INFINITY;
        #pragma unroll
        for (int kt4 = 0; kt4 < 4; kt4++)
            #pragma unroll
            for (int r = 0; r < 4; r++)
                tmax = fmaxf(tmax, st[kt4][r]);
        tmax = fmaxf(tmax, __shfl_xor(tmax, 16));
        tmax = fmaxf(tmax, __shfl_xor(tmax, 32));
        const float mnew = fmaxf(mrun, tmax);
        const float alpha = __expf(mrun - mnew);
        float p[4][4];
        float lsum = 0.f;
        #pragma unroll
        for (int kt4 = 0; kt4 < 4; kt4++)
            #pragma unroll
            for (int r = 0; r < 4; r++) {
                p[kt4][r] = __expf(st[kt4][r] - mnew);
                lsum += p[kt4][r];
            }
        lsum += __shfl_xor(lsum, 16);
        lsum += __shfl_xor(lsum, 32);
        lrun = lrun * alpha + lsum;
        mrun = mnew;
        // rescale O (O rows are q = hi*4+r -> broadcast alpha from lane q)
        #pragma unroll
        for (int r = 0; r < 4; r++) {
            const float ar = __shfl(alpha, hi * 4 + r);
            #pragma unroll
            for (int dj = 0; dj < 4; dj++) o[dj][r] *= ar;
        }
        // P -> LDS bf16 (per-wave buffer; wave-internal ordering via lgkmcnt)
        #pragma unroll
        for (int kt4 = 0; kt4 < 4; kt4++) {
            uint2 pk;
            pk.x = (unsigned)f2bf(p[kt4][0]) | ((unsigned)f2bf(p[kt4][1]) << 16);
            pk.y = (unsigned)f2bf(p[kt4][2]) | ((unsigned)f2bf(p[kt4][3]) << 16);
            *(uint2*)&Ps[w][ln][kt4 * 16 + hi * 4] = pk;
        }
        // PV: O[q][d] += P[q][key] * V[key][d]
        #pragma unroll
        for (int kc = 0; kc < 2; kc++) {
            short8 pa = *(const short8*)&Ps[w][ln][kc * 32 + hi * 8];
            #pragma unroll
            for (int dj = 0; dj < 4; dj++) {
                short8 vb = *(const short8*)&Vs[kc][hi][dj * 16 + ln][0];
                o[dj] = __builtin_amdgcn_mfma_f32_16x16x32_bf16(pa, vb, o[dj], 0, 0, 0);
            }
        }
    }

    const float inv = 1.f / lrun;          // lane's value is for q = ln
    #pragma unroll
    for (int r = 0; r < 4; r++) {
        const float ir = __shfl(inv, hi * 4 + r);
        const int s = q0 + w * 16 + hi * 4 + r;
        const size_t ob = ((size_t)(bh >> 4) * SS + s) * EE + (bh & 15) * 64;
        #pragma unroll
        for (int dj = 0; dj < 4; dj++)
            Cc[ob + dj * 16 + ln] = f2bf(o[dj][r] * ir);
    }
}

extern "C" void kernel_launch(void* const* d_in, const int* in_sizes, int n_in,
                              void* d_out, int out_size, void* d_ws, size_t ws_size,
                              hipStream_t stream)
{
    (void)in_sizes; (void)n_in; (void)out_size; (void)ws_size;
    const float* query = (const float*)d_in[0];
    const float* key   = (const float*)d_in[1];
    const float* value = (const float*)d_in[2];
    // d_in[3] = mask: exactly causal tril, implemented analytically
    const float* Wq = (const float*)d_in[4];
    const float* bq = (const float*)d_in[5];
    const float* Wk = (const float*)d_in[6];
    const float* bk = (const float*)d_in[7];
    const float* Wv = (const float*)d_in[8];
    const float* bv = (const float*)d_in[9];
    const float* Wo = (const float*)d_in[10];
    const float* bo = (const float*)d_in[11];
    float* out = (float*)d_out;

    // workspace layout (bytes), total = 64 MiB exactly
    char* ws = (char*)d_ws;
    u16* Xq = (u16*)(ws);                         // 8 MiB
    u16* Xk = (u16*)(ws + 8388608);               // 8 MiB
    u16* Xv = (u16*)(ws + 16777216);              // 8 MiB
    u16* Wqb = (u16*)(ws + 25165824);             // 2 MiB
    u16* Wkb = (u16*)(ws + 27262976);             // 2 MiB
    u16* Wvb = (u16*)(ws + 29360128);             // 2 MiB
    u16* Wob = (u16*)(ws + 31457280);             // 2 MiB
    u16* Qh  = (u16*)(ws + 33554432);             // 8 MiB [b,h][s][d]
    u16* Kh  = (u16*)(ws + 41943040);             // 8 MiB [b,h][s][d]
    u16* Vth = (u16*)(ws + 50331648);             // 8 MiB [b,h][d][s]
    u16* Cc  = (u16*)(ws + 58720256);             // 8 MiB [b][s][e]

    cvt_bf16<<<dim3(2048, 7), 256, 0, stream>>>(
        query, key, value, Wq, Wk, Wv, Wo,
        Xq, Xk, Xv, Wqb, Wkb, Wvb, Wob);

    dim3 gg(8, 32);   // N/128, M/128
    gemm_mfma<0><<<gg, 256, 0, stream>>>(Xq, Wqb, bq, Qh);
    gemm_mfma<1><<<gg, 256, 0, stream>>>(Xk, Wkb, bk, Kh);
    gemm_mfma<2><<<gg, 256, 0, stream>>>(Xv, Wvb, bv, Vth);
    attn_mfma<<<dim3(32, 32), 256, 0, stream>>>(Qh, Kh, Vth, Cc);
    gemm_mfma<3><<<gg, 256, 0, stream>>>(Cc, Wob, bo, out);
}

// Round 3
// 158.562 us; speedup vs baseline: 7.2426x; 1.2559x over previous
//
#include <hip/hip_runtime.h>
#include <math.h>

#define BB 2
#define SS 2048
#define EE 1024
#define HH 16
#define DD 64

typedef unsigned short u16;
typedef __attribute__((ext_vector_type(8))) short short8;
typedef __attribute__((ext_vector_type(4))) float f32x4;

__device__ __forceinline__ u16 f2bf(float x) {
    union { float f; unsigned u; } v; v.f = x;
    return (u16)((v.u + 0x7fffu + ((v.u >> 16) & 1u)) >> 16);
}

__device__ __forceinline__ float exp2_fast(float x) {
    float r;
    asm("v_exp_f32 %0, %1" : "=v"(r) : "v"(x));
    return r;
}

#define GLL16(gp, lp) \
    __builtin_amdgcn_global_load_lds( \
        (const __attribute__((address_space(1))) void*)(gp), \
        (__attribute__((address_space(3))) void*)(lp), 16, 0, 0)

// QSCALE = (1/sqrt(64)) * log2(e): softmax computed in base-2
#define QSCALE 0.18033688f

// ---------------------------------------------------------------------------
// fp32 -> bf16 conversion: z = 0..2 activations (4M elems), 3..6 weights (1M)
// ---------------------------------------------------------------------------
__global__ __launch_bounds__(256)
void cvt_bf16(const float* __restrict__ s0, const float* __restrict__ s1,
              const float* __restrict__ s2, const float* __restrict__ s3,
              const float* __restrict__ s4, const float* __restrict__ s5,
              const float* __restrict__ s6,
              u16* __restrict__ d0, u16* __restrict__ d1, u16* __restrict__ d2,
              u16* __restrict__ d3, u16* __restrict__ d4, u16* __restrict__ d5,
              u16* __restrict__ d6)
{
    const int z = blockIdx.y;
    const float* s; u16* d; int n;
    switch (z) {
        case 0: s = s0; d = d0; n = 4194304; break;
        case 1: s = s1; d = d1; n = 4194304; break;
        case 2: s = s2; d = d2; n = 4194304; break;
        case 3: s = s3; d = d3; n = 1048576; break;
        case 4: s = s4; d = d4; n = 1048576; break;
        case 5: s = s5; d = d5; n = 1048576; break;
        default: s = s6; d = d6; n = 1048576; break;
    }
    const int i = (blockIdx.x * 256 + threadIdx.x) * 8;
    if (i >= n) return;
    float4 a = *(const float4*)(s + i);
    float4 b = *(const float4*)(s + i + 4);
    short8 r;
    r[0] = (short)f2bf(a.x); r[1] = (short)f2bf(a.y);
    r[2] = (short)f2bf(a.z); r[3] = (short)f2bf(a.w);
    r[4] = (short)f2bf(b.x); r[5] = (short)f2bf(b.y);
    r[6] = (short)f2bf(b.z); r[7] = (short)f2bf(b.w);
    *(short8*)(d + i) = r;
}

// ---------------------------------------------------------------------------
// Fused QKV GEMM: one dispatch, blockIdx.z selects {Q,K,V}. 768 blocks -> 3/CU.
// C[m,n] = sum_k X[m,k]*W[n,k] + bias[n]; 128x128 tile, BK=32, 4 waves.
// z=0: Q scatter [b,h][s][d] scaled by QSCALE; z=1: K scatter [b,h][s][d];
// z=2: V scatter transposed [b,h][d][s].
// ---------------------------------------------------------------------------
__global__ __launch_bounds__(256)
void gemm_qkv(const u16* __restrict__ Xq, const u16* __restrict__ Xk,
              const u16* __restrict__ Xv,
              const u16* __restrict__ Wqb, const u16* __restrict__ Wkb,
              const u16* __restrict__ Wvb,
              const float* __restrict__ bq, const float* __restrict__ bk,
              const float* __restrict__ bv,
              u16* __restrict__ Qh, u16* __restrict__ Kh, u16* __restrict__ Vth)
{
    __shared__ __align__(16) u16 As[4][128][8];
    __shared__ __align__(16) u16 Bs[4][128][8];
    const int z = blockIdx.z;
    const u16* X = (z == 0) ? Xq : (z == 1) ? Xk : Xv;
    const u16* W = (z == 0) ? Wqb : (z == 1) ? Wkb : Wvb;
    const float* bias = (z == 0) ? bq : (z == 1) ? bk : bv;
    u16* out = (z == 0) ? Qh : (z == 1) ? Kh : Vth;

    const int t = threadIdx.x;
    const int w = t >> 6, l = t & 63;
    const int ln = l & 15, hi = l >> 4;
    const int m0 = blockIdx.y * 128, n0 = blockIdx.x * 128;
    const int wr = w >> 1, wc = w & 1;

    f32x4 acc[4][4];
    #pragma unroll
    for (int i = 0; i < 4; i++)
        #pragma unroll
        for (int j = 0; j < 4; j++)
            acc[i][j] = (f32x4){0.f, 0.f, 0.f, 0.f};

    for (int k0 = 0; k0 < 1024; k0 += 32) {
        __syncthreads();
        #pragma unroll
        for (int i = 0; i < 4; i++) {
            const int id = w + i * 4;
            const int tensor = id >> 3, kgrp = (id >> 1) & 3, mh = id & 1;
            const u16* g = tensor ? W : X;
            const int row = (tensor ? n0 : m0) + mh * 64 + l;
            const u16* gp = g + (size_t)row * 1024 + k0 + kgrp * 8;
            u16* lp = tensor ? &Bs[kgrp][mh * 64][0] : &As[kgrp][mh * 64][0];
            GLL16(gp, lp);
        }
        __syncthreads();
        short8 af[4], bfr[4];
        #pragma unroll
        for (int mi = 0; mi < 4; mi++)
            af[mi] = *(const short8*)&As[hi][wr * 64 + mi * 16 + ln][0];
        #pragma unroll
        for (int nj = 0; nj < 4; nj++)
            bfr[nj] = *(const short8*)&Bs[hi][wc * 64 + nj * 16 + ln][0];
        #pragma unroll
        for (int mi = 0; mi < 4; mi++)
            #pragma unroll
            for (int nj = 0; nj < 4; nj++)
                acc[mi][nj] = __builtin_amdgcn_mfma_f32_16x16x32_bf16(
                    af[mi], bfr[nj], acc[mi][nj], 0, 0, 0);
    }

    #pragma unroll
    for (int mi = 0; mi < 4; mi++) {
        #pragma unroll
        for (int nj = 0; nj < 4; nj++) {
            const int nb = n0 + wc * 64 + nj * 16 + ln;
            const float bv2 = bias[nb];
            #pragma unroll
            for (int r = 0; r < 4; r++) {
                const int m = m0 + wr * 64 + mi * 16 + hi * 4 + r;
                float v = acc[mi][nj][r] + bv2;
                if (z == 0) v *= QSCALE;
                const int b = m >> 11, s = m & 2047;
                const int h = nb >> 6, d = nb & 63;
                if (z == 2)
                    out[(((size_t)(b * HH + h) * 64 + d) << 11) + s] = f2bf(v);
                else
                    out[((((size_t)(b * HH + h)) << 11) + s) * 64 + d] = f2bf(v);
            }
        }
    }
}

// ---------------------------------------------------------------------------
// Output projection GEMM, 64x128 tile (512 blocks -> 2/CU), fp32 out + bias.
// ---------------------------------------------------------------------------
__global__ __launch_bounds__(256)
void gemm_out(const u16* __restrict__ Xb, const u16* __restrict__ Wb,
              const float* __restrict__ bias, float* __restrict__ outp)
{
    __shared__ __align__(16) u16 As[4][64][8];    // 4 KB
    __shared__ __align__(16) u16 Bs[4][128][8];   // 8 KB
    const int t = threadIdx.x;
    const int w = t >> 6, l = t & 63;
    const int ln = l & 15, hi = l >> 4;
    const int m0 = blockIdx.y * 64, n0 = blockIdx.x * 128;
    const int wr = w >> 1, wc = w & 1;

    f32x4 acc[2][4];
    #pragma unroll
    for (int i = 0; i < 2; i++)
        #pragma unroll
        for (int j = 0; j < 4; j++)
            acc[i][j] = (f32x4){0.f, 0.f, 0.f, 0.f};

    for (int k0 = 0; k0 < 1024; k0 += 32) {
        __syncthreads();
        #pragma unroll
        for (int i = 0; i < 3; i++) {
            const int id = w + i * 4;              // 0..11
            if (id < 4) {
                const u16* gp = Xb + (size_t)(m0 + l) * 1024 + k0 + id * 8;
                GLL16(gp, &As[id][0][0]);
            } else {
                const int idb = id - 4, kg = idb & 3, half = idb >> 2;
                const u16* gp = Wb + (size_t)(n0 + half * 64 + l) * 1024 + k0 + kg * 8;
                GLL16(gp, &Bs[kg][half * 64][0]);
            }
        }
        __syncthreads();
        short8 af[2], bfr[4];
        #pragma unroll
        for (int mi = 0; mi < 2; mi++)
            af[mi] = *(const short8*)&As[hi][wr * 32 + mi * 16 + ln][0];
        #pragma unroll
        for (int nj = 0; nj < 4; nj++)
            bfr[nj] = *(const short8*)&Bs[hi][wc * 64 + nj * 16 + ln][0];
        #pragma unroll
        for (int mi = 0; mi < 2; mi++)
            #pragma unroll
            for (int nj = 0; nj < 4; nj++)
                acc[mi][nj] = __builtin_amdgcn_mfma_f32_16x16x32_bf16(
                    af[mi], bfr[nj], acc[mi][nj], 0, 0, 0);
    }

    #pragma unroll
    for (int mi = 0; mi < 2; mi++) {
        #pragma unroll
        for (int nj = 0; nj < 4; nj++) {
            const int nb = n0 + wc * 64 + nj * 16 + ln;
            const float bv2 = bias[nb];
            #pragma unroll
            for (int r = 0; r < 4; r++) {
                const int m = m0 + wr * 32 + mi * 16 + hi * 4 + r;
                outp[(size_t)m * 1024 + nb] = acc[mi][nj][r] + bv2;
            }
        }
    }
}

// ---------------------------------------------------------------------------
// Flash attention, bf16 MFMA v2. Q,K: [b,h][s][d] bf16 (Q scaled by QSCALE),
// Vt: [b,h][d][s] bf16. Output concat [b][s][e] bf16.
// 4 waves x 16 q rows, KBLK=64, double-buffered K/V (loads issued before
// compute, one barrier/iter), base-2 online softmax with deferred-max (THR=8),
// v_cvt_pk_bf16_f32 P-pack, XOR-granule-swizzled Ps (conflict-free).
// ---------------------------------------------------------------------------
__global__ __launch_bounds__(256)
void attn_mfma(const u16* __restrict__ Qh, const u16* __restrict__ Kh,
               const u16* __restrict__ Vt, u16* __restrict__ Cc)
{
    __shared__ __align__(16) u16 Ks[2][2][4][64][8];  // [buf][dchunk][kgrp][key][8] 16KB
    __shared__ __align__(16) u16 Vs[2][2][4][64][8];  // [buf][keychunk][kgrp][d][8] 16KB
    __shared__ __align__(16) u16 Ps[4][16][64];       // [wave][q][key] swizzled 8KB
    const int bh = blockIdx.x;
    const int y  = 31 - blockIdx.y;        // longest blocks dispatch first
    const int q0 = y * 64;
    const int t = threadIdx.x, w = t >> 6, l = t & 63;
    const int ln = l & 15, hi = l >> 4;
    const size_t base = (size_t)bh * SS * DD;
    const int qg = q0 + w * 16 + ln;       // this lane's query row

    short8 qf0, qf1;
    {
        const u16* qp = Qh + base + (size_t)qg * 64 + hi * 8;
        qf0 = *(const short8*)qp;
        qf1 = *(const short8*)(qp + 32);
    }
    f32x4 o[4];
    #pragma unroll
    for (int dj = 0; dj < 4; dj++) o[dj] = (f32x4){0.f, 0.f, 0.f, 0.f};
    float mrun = -INFINITY, lrun = 0.f;

#define STAGE(buf, key0_)                                                        \
    {                                                                            \
        _Pragma("unroll")                                                        \
        for (int i_ = 0; i_ < 4; i_++) {                                         \
            const int id_ = w + i_ * 4;                                          \
            if (id_ < 8) {                                                       \
                const int dc_ = id_ >> 2, kg_ = id_ & 3;                         \
                const u16* gp_ = Kh + base + (size_t)((key0_) + l) * 64          \
                                 + dc_ * 32 + kg_ * 8;                           \
                GLL16(gp_, &Ks[buf][dc_][kg_][0][0]);                            \
            } else {                                                             \
                const int kc_ = (id_ >> 2) & 1, kg_ = id_ & 3;                   \
                const u16* gp_ = Vt + base + (size_t)l * SS + (key0_)            \
                                 + kc_ * 32 + kg_ * 8;                           \
                GLL16(gp_, &Vs[buf][kc_][kg_][0][0]);                            \
            }                                                                    \
        }                                                                        \
    }

    STAGE(0, 0);
    __syncthreads();
    int cur = 0;
    const int nkt = y + 1;
    for (int kt = 0; kt < nkt; kt++) {
        const int key0 = kt * 64;
        if (kt + 1 < nkt) STAGE(cur ^ 1, key0 + 64);   // prefetch next tile

        // QK^T (swapped): rows=keys, cols=q
        f32x4 st[4];
        #pragma unroll
        for (int kt4 = 0; kt4 < 4; kt4++) {
            short8 ka = *(const short8*)&Ks[cur][0][hi][kt4 * 16 + ln][0];
            short8 kb = *(const short8*)&Ks[cur][1][hi][kt4 * 16 + ln][0];
            f32x4 zz = (f32x4){0.f, 0.f, 0.f, 0.f};
            zz = __builtin_amdgcn_mfma_f32_16x16x32_bf16(ka, qf0, zz, 0, 0, 0);
            zz = __builtin_amdgcn_mfma_f32_16x16x32_bf16(kb, qf1, zz, 0, 0, 0);
            st[kt4] = zz;
        }
        if (kt == y) {  // diagonal tile: causal mask
            #pragma unroll
            for (int kt4 = 0; kt4 < 4; kt4++)
                #pragma unroll
                for (int r = 0; r < 4; r++)
                    if (key0 + kt4 * 16 + hi * 4 + r > qg)
                        st[kt4][r] = -INFINITY;
        }

        // online softmax (base-2), state per lane for q = ln
        float tmax = -INFINITY;
        #pragma unroll
        for (int kt4 = 0; kt4 < 4; kt4++)
            #pragma unroll
            for (int r = 0; r < 4; r++)
                tmax = fmaxf(tmax, st[kt4][r]);
        tmax = fmaxf(tmax, __shfl_xor(tmax, 16));
        tmax = fmaxf(tmax, __shfl_xor(tmax, 32));
        if (__ballot(tmax > mrun + 8.f)) {      // deferred-max rescale (T13)
            const float mnew = fmaxf(mrun, tmax);
            const float alpha = exp2_fast(mrun - mnew);
            lrun *= alpha;
            mrun = mnew;
            #pragma unroll
            for (int r = 0; r < 4; r++) {
                const float ar = __shfl(alpha, hi * 4 + r);
                #pragma unroll
                for (int dj = 0; dj < 4; dj++) o[dj][r] *= ar;
            }
        }
        float p[4][4];
        float lsum = 0.f;
        #pragma unroll
        for (int kt4 = 0; kt4 < 4; kt4++)
            #pragma unroll
            for (int r = 0; r < 4; r++) {
                p[kt4][r] = exp2_fast(st[kt4][r] - mrun);
                lsum += p[kt4][r];
            }
        lsum += __shfl_xor(lsum, 16);
        lsum += __shfl_xor(lsum, 32);
        lrun += lsum;

        // P -> LDS bf16, XOR-granule swizzle (conflict-free b64 writes)
        char* prow = ((char*)Ps) + (w * 16 + ln) * 128 + (hi & 1) * 8;
        #pragma unroll
        for (int kt4 = 0; kt4 < 4; kt4++) {
            unsigned dw0, dw1;
            asm("v_cvt_pk_bf16_f32 %0, %1, %2" : "=v"(dw0)
                : "v"(p[kt4][0]), "v"(p[kt4][1]));
            asm("v_cvt_pk_bf16_f32 %0, %1, %2" : "=v"(dw1)
                : "v"(p[kt4][2]), "v"(p[kt4][3]));
            const int g = (2 * kt4 + (hi >> 1)) ^ (ln & 7);
            *(uint2*)(prow + g * 16) = make_uint2(dw0, dw1);
        }

        // PV: O[q][d] += P[q][key] * V[key][d]
        #pragma unroll
        for (int kc = 0; kc < 2; kc++) {
            const int gr = (kc * 4 + hi) ^ (ln & 7);
            short8 pa = *(const short8*)(((char*)Ps) + (w * 16 + ln) * 128 + gr * 16);
            #pragma unroll
            for (int dj = 0; dj < 4; dj++) {
                short8 vb = *(const short8*)&Vs[cur][kc][hi][dj * 16 + ln][0];
                o[dj] = __builtin_amdgcn_mfma_f32_16x16x32_bf16(pa, vb, o[dj], 0, 0, 0);
            }
        }
        __syncthreads();   // next-tile loads landed; everyone done with cur
        cur ^= 1;
    }
#undef STAGE

    const float inv = 1.f / lrun;          // lane's value is for q = ln
    #pragma unroll
    for (int r = 0; r < 4; r++) {
        const float ir = __shfl(inv, hi * 4 + r);
        const int s = q0 + w * 16 + hi * 4 + r;
        const size_t ob = ((size_t)(bh >> 4) * SS + s) * EE + (bh & 15) * 64;
        #pragma unroll
        for (int dj = 0; dj < 4; dj++)
            Cc[ob + dj * 16 + ln] = f2bf(o[dj][r] * ir);
    }
}

extern "C" void kernel_launch(void* const* d_in, const int* in_sizes, int n_in,
                              void* d_out, int out_size, void* d_ws, size_t ws_size,
                              hipStream_t stream)
{
    (void)in_sizes; (void)n_in; (void)out_size; (void)ws_size;
    const float* query = (const float*)d_in[0];
    const float* key   = (const float*)d_in[1];
    const float* value = (const float*)d_in[2];
    // d_in[3] = mask: exactly causal tril, implemented analytically
    const float* Wq = (const float*)d_in[4];
    const float* bq = (const float*)d_in[5];
    const float* Wk = (const float*)d_in[6];
    const float* bk = (const float*)d_in[7];
    const float* Wv = (const float*)d_in[8];
    const float* bv = (const float*)d_in[9];
    const float* Wo = (const float*)d_in[10];
    const float* bo = (const float*)d_in[11];
    float* out = (float*)d_out;

    char* ws = (char*)d_ws;
    u16* Xq = (u16*)(ws);                         // 8 MiB
    u16* Xk = (u16*)(ws + 8388608);               // 8 MiB
    u16* Xv = (u16*)(ws + 16777216);              // 8 MiB
    u16* Wqb = (u16*)(ws + 25165824);             // 2 MiB
    u16* Wkb = (u16*)(ws + 27262976);             // 2 MiB
    u16* Wvb = (u16*)(ws + 29360128);             // 2 MiB
    u16* Wob = (u16*)(ws + 31457280);             // 2 MiB
    u16* Qh  = (u16*)(ws + 33554432);             // 8 MiB [b,h][s][d]
    u16* Kh  = (u16*)(ws + 41943040);             // 8 MiB [b,h][s][d]
    u16* Vth = (u16*)(ws + 50331648);             // 8 MiB [b,h][d][s]
    u16* Cc  = (u16*)(ws + 58720256);             // 8 MiB [b][s][e]

    cvt_bf16<<<dim3(2048, 7), 256, 0, stream>>>(
        query, key, value, Wq, Wk, Wv, Wo,
        Xq, Xk, Xv, Wqb, Wkb, Wvb, Wob);

    gemm_qkv<<<dim3(8, 32, 3), 256, 0, stream>>>(
        Xq, Xk, Xv, Wqb, Wkb, Wvb, bq, bk, bv, Qh, Kh, Vth);
    attn_mfma<<<dim3(32, 32), 256, 0, stream>>>(Qh, Kh, Vth, Cc);
    gemm_out<<<dim3(8, 64), 256, 0, stream>>>(Cc, Wob, bo, out);
}